// Round 1
// 131.729 us; speedup vs baseline: 1.0078x; 1.0078x over previous
//
#include <hip/hip_runtime.h>
#include <math.h>

// Problem constants
#define BB 2
#define CC 64
#define NN 4096      // 16*16*16
#define CN (CC*NN)
#define NJ 8         // j-split chunks for flash partials
#define NT ((NN/NJ)/64)   // 8 j-tiles per chunk

#define LOG2E 1.4426950408889634f
#define QSCALE 0.18033688011112042f   // log2e / sqrt(64)
#define RESC_THR 8.0f                 // defer-max threshold (log2 domain)

#define XT_ROWS 4097                  // row 0 = zero guard row
#define WQKV_OFF (27*80*64)           // conv-tap reorg size

typedef __attribute__((ext_vector_type(8))) short short8;
typedef __attribute__((ext_vector_type(4))) float float4v;
typedef unsigned short ushortT;

__device__ __forceinline__ ushortT f2bf(float x) {
    union { float f; unsigned u; } v; v.f = x;
    unsigned r = v.u + 0x7FFF + ((v.u >> 16) & 1);   // RNE
    return (ushortT)(r >> 16);
}
__device__ __forceinline__ float bf2f(short s) {
    union { unsigned u; float f; } v;
    v.u = ((unsigned)(unsigned short)s) << 16;
    return v.f;
}
// pack 2 fp32 -> 1 VGPR holding 2 bf16: low16 = bf(a), high16 = bf(b)
__device__ __forceinline__ unsigned pk2(float a, float b) {
    unsigned ua = __float_as_uint(a) + 0x8000u;
    unsigned ub = __float_as_uint(b) + 0x8000u;
    return __builtin_amdgcn_perm(ub, ua, 0x07060302);
}

// ---------------- PE table value: global channel c (0..63), coord 0..15 ----------------
__device__ __forceinline__ float pe_tab_val(int c, int pos) {
    int c2 = (c < 22) ? c : (c < 44) ? (c - 22) : (c - 44);
    int is_cos = (c2 >= 11);
    int k = c2 - (is_cos ? 11 : 0);
    float freq = exp2f(-1.2079738526863135f * (float)k);
    float arg = (float)pos * freq;
    return is_cos ? cosf(arg) : sinf(arg);
}

// ---------------- Merged: x_pe + Xt + QKV (blocks 0..127) | conv weight reorg (blocks 128..) ----------------
__global__ __launch_bounds__(256) void k_pre(const float* __restrict__ x,
                                             const float* __restrict__ qw,
                                             const float* __restrict__ kw,
                                             const float* __restrict__ vw,
                                             const float* __restrict__ Wq,
                                             const float* __restrict__ Wk,
                                             const float* __restrict__ Wv,
                                             float* __restrict__ xpe,
                                             ushortT* __restrict__ Xt,
                                             ushortT* __restrict__ Wr,
                                             ushortT* __restrict__ Qb,
                                             ushortT* __restrict__ Kb,
                                             ushortT* __restrict__ Vtb) {
    int blk = blockIdx.x, t = threadIdx.x;
    if (blk < 128) {
        __shared__ float sT[64][65];       // fp32 x_pe tile (ch-major)
        __shared__ float sPE[64][17];
        __shared__ ushortT sWt[64][72];    // transposed bf16 weights (d-major)
        __shared__ ushortT sVt[64][72];    // V transpose / QK store staging
        int b = blk >> 6, pos0 = (blk & 63) * 64;

        // PE table
        #pragma unroll
        for (int k = 0; k < 4; k++) {
            int e = t + k * 256;           // 0..1023
            int c = e >> 4, coord = e & 15;
            sPE[c][coord] = pe_tab_val(c, coord);
        }
        __syncthreads();

        // x + PE -> sT, xpe
        int pin = t & 63, cg0 = t >> 6;
        #pragma unroll
        for (int pass = 0; pass < 16; pass++) {
            int c = pass * 4 + cg0;
            int pos = pos0 + pin;
            int coord = (c < 22) ? (pos >> 8) : (c < 44) ? ((pos >> 4) & 15) : (pos & 15);
            size_t gi = (size_t)(b * 64 + c) * NN + pos;
            float v = x[gi] + sPE[c][coord];
            xpe[gi] = v;
            sT[c][pin] = v;
        }
        __syncthreads();

        // Xt store (transposed bf16, guard row) — vectorized short8 stores
        {
            int po = t & 63, cg = t >> 6;
            #pragma unroll
            for (int half = 0; half < 2; half++) {
                int c0 = cg * 8 + half * 32;
                union { ushortT u[8]; short8 s; } pk_;
                #pragma unroll
                for (int e = 0; e < 8; e++) pk_.u[e] = f2bf(sT[c0 + e][po]);
                *(short8*)(Xt + ((size_t)b * XT_ROWS + pos0 + po + 1) * 64 + c0) = pk_.s;
            }
            if ((blk & 63) == 0 && t < 64)
                Xt[((size_t)b * XT_ROWS) * 64 + t] = 0;
        }

        // A-frags (token rows) from sT
        int w = t >> 6, l = t & 63, lane15 = l & 15, q = l >> 4;
        int row = w * 16 + lane15;
        short8 a0, a1;
        {
            union { ushortT u[8]; short8 s; } t0, t1;
            #pragma unroll
            for (int e = 0; e < 8; e++) {
                t0.u[e] = f2bf(sT[q * 8 + e][row]);
                t1.u[e] = f2bf(sT[32 + q * 8 + e][row]);
            }
            a0 = t0.s; a1 = t1.s;
        }

        // QKV via MFMA, weights staged per mat
        #pragma unroll
        for (int mat = 0; mat < 3; mat++) {
            const float* Wm = (mat == 0) ? Wq : (mat == 1) ? Wk : Wv;
            float sc = (mat == 0) ? QSCALE : 1.f;
            __syncthreads();   // protect sWt/sVt reuse
            #pragma unroll
            for (int p = 0; p < 4; p++) {
                int idx = t + p * 256;     // 0..1023
                int c = idx >> 4, d4 = (idx & 15) * 4;
                float4 wv = *(const float4*)&Wm[c * 64 + d4];
                sWt[d4 + 0][c] = f2bf(wv.x * sc);
                sWt[d4 + 1][c] = f2bf(wv.y * sc);
                sWt[d4 + 2][c] = f2bf(wv.z * sc);
                sWt[d4 + 3][c] = f2bf(wv.w * sc);
            }
            __syncthreads();

            float4v acc[4];
            #pragma unroll
            for (int cg = 0; cg < 4; cg++) {
                const ushortT* wrow = &sWt[cg * 16 + lane15][0];
                short8 b0 = *(const short8*)(wrow + q * 8);
                short8 b1 = *(const short8*)(wrow + 32 + q * 8);
                float4v a = (float4v)0.f;
                a = __builtin_amdgcn_mfma_f32_16x16x32_bf16(a0, b0, a, 0, 0, 0);
                a = __builtin_amdgcn_mfma_f32_16x16x32_bf16(a1, b1, a, 0, 0, 0);
                acc[cg] = a;
            }
            if (mat < 2) {
                // stage [pos][ch] in LDS, then coalesced short8 stores
                #pragma unroll
                for (int cg = 0; cg < 4; cg++)
                    #pragma unroll
                    for (int r = 0; r < 4; r++)
                        sVt[w * 16 + q * 4 + r][cg * 16 + lane15] = f2bf(acc[cg][r]);
                __syncthreads();
                ushortT* o = (mat == 0) ? Qb : Kb;
                int pl = t >> 2, sg = t & 3;
                short8 v0 = *(const short8*)&sVt[pl][sg * 16];
                short8 v1 = *(const short8*)&sVt[pl][sg * 16 + 8];
                size_t bq = ((size_t)(b * NN + pos0 + pl)) * 64 + sg * 16;
                *(short8*)(o + bq) = v0;
                *(short8*)(o + bq + 8) = v1;
            } else {
                #pragma unroll
                for (int cg = 0; cg < 4; cg++)
                    #pragma unroll
                    for (int r = 0; r < 4; r++)
                        sVt[cg * 16 + lane15][w * 16 + q * 4 + r] = f2bf(acc[cg][r]);
                __syncthreads();
                int c2 = t >> 2, seg = t & 3;
                short8 v0 = *(const short8*)&sVt[c2][seg * 16];
                short8 v1 = *(const short8*)&sVt[c2][seg * 16 + 8];
                size_t base = ((size_t)(b * 64 + c2)) * NN + pos0 + seg * 16;
                *(short8*)(Vtb + base) = v0;
                *(short8*)(Vtb + base + 8) = v1;
            }
        }
    } else {
        // conv-tap weight reorg: Wr[tap][oc(80)][ic]
        int idx = (blk - 128) * 256 + t;
        if (idx < WQKV_OFF) {
            int ic = idx & 63;
            int oc = (idx >> 6) % 80;
            int tap = idx / 5120;
            float v;
            if (oc < 8)       v = qw[(oc * 64 + ic) * 27 + tap] * LOG2E;
            else if (oc < 16) v = kw[((oc - 8) * 64 + ic) * 27 + tap];
            else              v = vw[((oc - 16) * 64 + ic) * 27 + tap];
            Wr[idx] = f2bf(v);
        }
    }
}

// ---------------- LDS staging helpers for flash ----------------
template<int IS_TSA>
__device__ __forceinline__ void stage_load(short8* kst, short8* vst,
                                           const ushortT* __restrict__ Km,
                                           const ushortT* __restrict__ Vt,
                                           int b, int jb, int t) {
    if (IS_TSA) {
        #pragma unroll
        for (int ps = 0; ps < 2; ps++) {
            int idx = ps * 256 + t, j = idx >> 3, g = idx & 7;
            kst[ps] = *(const short8*)(Km + ((size_t)(b * NN + jb + j)) * 64 + g * 8);
        }
    } else {
        if (t < 64)
            kst[0] = *(const short8*)(Km + ((size_t)(b * NN + jb + t)) * 8);
    }
    #pragma unroll
    for (int ps = 0; ps < 2; ps++) {
        int idx = ps * 256 + t, c = idx >> 3, gj = idx & 7;
        vst[ps] = *(const short8*)(Vt + ((size_t)(b * 64 + c)) * NN + jb + gj * 8);
    }
}

template<int IS_TSA>
__device__ __forceinline__ void stage_write(const short8* kst, const short8* vst,
                                            ushortT* sK, ushortT* sV, int t) {
    if (IS_TSA) {
        #pragma unroll
        for (int ps = 0; ps < 2; ps++) {
            int idx = ps * 256 + t, j = idx >> 3, g = idx & 7;
            *(short8*)(sK + j * 64 + ((g ^ (j & 7)) * 8)) = kst[ps];
        }
    } else {
        if (t < 64)
            *(short8*)(sK + t * 64 + ((t & 7) * 8)) = kst[0];
    }
    #pragma unroll
    for (int ps = 0; ps < 2; ps++) {
        int idx = ps * 256 + t, c = idx >> 3, gj = idx & 7;
        *(short8*)(sV + c * 64 + ((gj ^ (c & 7)) * 8)) = vst[ps];
    }
}

// ---------------- MFMA flash body: 2 i-subtiles per wave ----------------
template<int IS_TSA>
__device__ __forceinline__ void flash_body(int it, int jc, int b, int t,
                                           const ushortT* __restrict__ Qm,
                                           const ushortT* __restrict__ Km,
                                           const ushortT* __restrict__ Vt,
                                           float* __restrict__ pM,
                                           float* __restrict__ pL,
                                           ushortT* __restrict__ pAcc,
                                           ushortT* __restrict__ sKb,
                                           ushortT* __restrict__ sVb,
                                           ushortT* __restrict__ sPall) {
    constexpr int KCH = IS_TSA ? 2 : 1;
    constexpr int DQ  = IS_TSA ? 64 : 8;
    int w = t >> 6, l = t & 63;
    int lane15 = l & 15, q = l >> 4;
    int i0a = it * 128 + w * 16;
    ushortT* myP = sPall + w * (16 * 64);

    short8 qf[2][KCH];
    #pragma unroll
    for (int si = 0; si < 2; si++) {
        const ushortT* qrow = Qm + ((size_t)(b * NN + i0a + si * 64 + lane15)) * DQ;
        if (IS_TSA) {
            qf[si][0] = *(const short8*)(qrow + q * 8);
            qf[si][1] = *(const short8*)(qrow + 32 + q * 8);
        } else {
            short8 z = (short8)0;
            if (q == 0) z = *(const short8*)qrow;
            qf[si][0] = z;
        }
    }

    float m_run[2] = {-3e38f, -3e38f}, Lacc[2] = {0.f, 0.f};
    float4v O[2][4];
    #pragma unroll
    for (int si = 0; si < 2; si++)
        #pragma unroll
        for (int cs = 0; cs < 4; cs++) O[si][cs] = (float4v)0.f;

    const int jbase0 = jc * (NN / NJ);

    short8 kst[2], vst[2];
    stage_load<IS_TSA>(kst, vst, Km, Vt, b, jbase0, t);
    stage_write<IS_TSA>(kst, vst, sKb, sVb, t);
    __syncthreads();

    for (int jt = 0; jt < NT; jt++) {
        int cur = jt & 1;
        ushortT* cK = sKb + cur * 4096;
        ushortT* cV = sVb + cur * 4096;
        bool more = (jt + 1 < NT);

        if (more) stage_load<IS_TSA>(kst, vst, Km, Vt, b, jbase0 + (jt + 1) * 64, t);

        short8 kf[4][KCH];
        #pragma unroll
        for (int sub = 0; sub < 4; sub++) {
            int jr = sub * 16 + lane15;
            if (IS_TSA) {
                kf[sub][0] = *(const short8*)(cK + jr * 64 + (((0 * 4 + q) ^ (lane15 & 7)) * 8));
                kf[sub][1] = *(const short8*)(cK + jr * 64 + (((1 * 4 + q) ^ (lane15 & 7)) * 8));
            } else {
                short8 z = (short8)0;
                if (q == 0) z = *(const short8*)(cK + jr * 64 + ((lane15 & 7) * 8));
                kf[sub][0] = z;
            }
        }

        float4v s[2][4];
        #pragma unroll
        for (int si = 0; si < 2; si++)
            #pragma unroll
            for (int sub = 0; sub < 4; sub++) {
                float4v acc = (float4v)0.f;
                #pragma unroll
                for (int kc = 0; kc < KCH; kc++)
                    acc = __builtin_amdgcn_mfma_f32_16x16x32_bf16(kf[sub][kc], qf[si][kc], acc, 0, 0, 0);
                s[si][sub] = acc;
            }

        short8 va[4], vbf[4];
        #pragma unroll
        for (int sub = 0; sub < 4; sub++) {
            int cr = sub * 16 + lane15;
            va[sub]  = *(const short8*)(cV + cr * 64 + ((q ^ (lane15 & 7)) * 8));
            vbf[sub] = *(const short8*)(cV + cr * 64 + (((4 + q) ^ (lane15 & 7)) * 8));
        }

        #pragma unroll
        for (int si = 0; si < 2; si++) {
            float tmax = fmaxf(fmaxf(fmaxf(s[si][0][0], s[si][0][1]), fmaxf(s[si][0][2], s[si][0][3])),
                               fmaxf(fmaxf(s[si][1][0], s[si][1][1]), fmaxf(s[si][1][2], s[si][1][3])));
            float tmax2 = fmaxf(fmaxf(fmaxf(s[si][2][0], s[si][2][1]), fmaxf(s[si][2][2], s[si][2][3])),
                                fmaxf(fmaxf(s[si][3][0], s[si][3][1]), fmaxf(s[si][3][2], s[si][3][3])));
            tmax = fmaxf(tmax, tmax2);
            tmax = fmaxf(tmax, __shfl_xor(tmax, 16));
            tmax = fmaxf(tmax, __shfl_xor(tmax, 32));

            // T13 defer-max: only rescale when some row's max grew by > THR.
            // P values then bounded by 2^THR; f32 accum absorbs it.
            if (!__all(tmax <= m_run[si] + RESC_THR)) {
                float mnew = fmaxf(m_run[si], tmax);
                float corr = exp2f(m_run[si] - mnew);
                Lacc[si] *= corr;
                float c0 = __shfl(corr, q * 4 + 0);
                float c1 = __shfl(corr, q * 4 + 1);
                float c2 = __shfl(corr, q * 4 + 2);
                float c3 = __shfl(corr, q * 4 + 3);
                #pragma unroll
                for (int cs = 0; cs < 4; cs++) {
                    O[si][cs][0] *= c0; O[si][cs][1] *= c1;
                    O[si][cs][2] *= c2; O[si][cs][3] *= c3;
                }
                m_run[si] = mnew;
            }
            float mcur = m_run[si];

            #pragma unroll
            for (int sub = 0; sub < 4; sub++) {
                float p0 = exp2f(s[si][sub][0] - mcur);
                float p1 = exp2f(s[si][sub][1] - mcur);
                float p2 = exp2f(s[si][sub][2] - mcur);
                float p3 = exp2f(s[si][sub][3] - mcur);
                Lacc[si] += (p0 + p1) + (p2 + p3);
                unsigned lo = pk2(p0, p1), hi = pk2(p2, p3);
                int g = sub * 2 + (q >> 1);
                unsigned* wp = (unsigned*)(myP + lane15 * 64 + ((g ^ (lane15 & 7)) * 8) + (q & 1) * 4);
                wp[0] = lo; wp[1] = hi;
            }

            short8 pf0 = *(const short8*)(myP + lane15 * 64 + (((0 * 4 + q) ^ (lane15 & 7)) * 8));
            short8 pf1 = *(const short8*)(myP + lane15 * 64 + (((1 * 4 + q) ^ (lane15 & 7)) * 8));

            #pragma unroll
            for (int sub = 0; sub < 4; sub++) {
                O[si][sub] = __builtin_amdgcn_mfma_f32_16x16x32_bf16(pf0, va[sub], O[si][sub], 0, 0, 0);
                O[si][sub] = __builtin_amdgcn_mfma_f32_16x16x32_bf16(pf1, vbf[sub], O[si][sub], 0, 0, 0);
            }
        }

        if (more)
            stage_write<IS_TSA>(kst, vst, sKb + (cur ^ 1) * 4096, sVb + (cur ^ 1) * 4096, t);
        __syncthreads();
    }

    // Epilogue: stage O through per-wave LDS (swizzled) -> coalesced short8 stores
    #pragma unroll
    for (int si = 0; si < 2; si++) {
        size_t base = (size_t)(b * NJ + jc) * NN + i0a + si * 64;
        float Ls = Lacc[si];
        Ls += __shfl_xor(Ls, 16);
        Ls += __shfl_xor(Ls, 32);
        if (q == 0) {
            pL[base + lane15] = Ls;
            pM[base + lane15] = m_run[si];
        }
        #pragma unroll
        for (int cs = 0; cs < 4; cs++) {
            int g = cs * 2 + (lane15 >> 3);
            #pragma unroll
            for (int r = 0; r < 4; r++) {
                int rr = q * 4 + r;
                myP[rr * 64 + ((g ^ (rr & 7)) * 8) + (lane15 & 7)] = f2bf(O[si][cs][r]);
            }
        }
        int rrow = l >> 2, rs2 = (l & 3) * 2;
        short8 ov0 = *(const short8*)(myP + rrow * 64 + ((rs2 ^ (rrow & 7)) * 8));
        short8 ov1 = *(const short8*)(myP + rrow * 64 + (((rs2 + 1) ^ (rrow & 7)) * 8));
        size_t gb = (base + rrow) * 64 + (l & 3) * 16;
        *(short8*)(pAcc + gb) = ov0;
        *(short8*)(pAcc + gb + 8) = ov1;
    }
}

// ---------------- Reduce one partial set ----------------
__device__ __forceinline__ void reduce_set(const float* __restrict__ pM,
                                           const float* __restrict__ pL,
                                           const ushortT* __restrict__ pAcc,
                                           int b, int n, int seg, float* v) {
    float mv[NJ], M = -3e38f;
    #pragma unroll
    for (int jcc = 0; jcc < NJ; jcc++) {
        mv[jcc] = pM[(size_t)(b * NJ + jcc) * NN + n];
        M = fmaxf(M, mv[jcc]);
    }
    float L = 0.f;
    #pragma unroll
    for (int e = 0; e < 8; e++) v[e] = 0.f;
    #pragma unroll
    for (int jcc = 0; jcc < NJ; jcc++) {
        size_t rb = (size_t)(b * NJ + jcc) * NN + n;
        float wgt = exp2f(mv[jcc] - M);
        L += pL[rb] * wgt;
        short8 x0 = *(const short8*)(pAcc + rb * 64 + seg * 8);
        #pragma unroll
        for (int e = 0; e < 8; e++) v[e] += wgt * bf2f(x0[e]);
    }
    float invL = 1.f / L;
    #pragma unroll
    for (int e = 0; e < 8; e++) v[e] *= invL;
}

// ---------------- Fused: conv (blocks 0..127) + TSA flash (blocks 128..639) ----------------
__global__ __launch_bounds__(256, 3) void k_tsacv(const ushortT* __restrict__ Qb,
                                                  const ushortT* __restrict__ Kb,
                                                  const ushortT* __restrict__ Vtb,
                                                  const ushortT* __restrict__ Xt,
                                                  const ushortT* __restrict__ Wr,
                                                  const float* __restrict__ qb,
                                                  const float* __restrict__ kb,
                                                  const float* __restrict__ vb,
                                                  ushortT* __restrict__ Mt,
                                                  ushortT* __restrict__ Nt,
                                                  ushortT* __restrict__ Wvt,
                                                  float* __restrict__ pMt, float* __restrict__ pLt,
                                                  ushortT* __restrict__ pAccT) {
    __shared__ ushortT sm[20480];   // 40 KB: flash K/V/P | conv W double-buffer
    int bx = blockIdx.x, t = threadIdx.x;
    if (bx >= 128) {
        int fb = bx - 128;                 // 0..511
        int it = fb & 31, jc = (fb >> 5) & 7, b = fb >> 8;
        flash_body<1>(it, jc, b, t, Qb, Kb, Vtb, pMt, pLt, pAccT,
                      sm, sm + 8192, sm + 16384);
    } else {
        int cv = bx;                       // 0..127
        int tile = cv & 63, b = cv >> 6;
        int w = t >> 6, l = t & 63, lane15 = l & 15, q = l >> 4;
        int pos0 = tile * 64 + w * 16;
        const ushortT* xb = Xt + (size_t)b * XT_ROWS * 64;
        int pos = pos0 + lane15;
        int dz = pos & 15, wy = (pos >> 4) & 15, hx = pos >> 8;

        ushortT* sW = sm;                  // 2 x 5120 ushorts

        float4v accA[5], accB[5];
        #pragma unroll
        for (int o = 0; o < 5; o++) { accA[o] = (float4v)0.f; accB[o] = (float4v)0.f; }

        short8 ws[3];
        auto ldW = [&](int tap) {
            #pragma unroll
            for (int c3 = 0; c3 < 3; c3++) {
                int idx = t + c3 * 256;
                if (idx < 640)
                    ws[c3] = *(const short8*)(Wr + (size_t)tap * 5120 + idx * 8);
            }
        };
        auto wrW = [&](ushortT* buf) {
            #pragma unroll
            for (int c3 = 0; c3 < 3; c3++) {
                int idx = t + c3 * 256;
                if (idx < 640) {
                    int row = idx >> 3, g = idx & 7;
                    *(short8*)(buf + row * 64 + ((g ^ (row & 7)) * 8)) = ws[c3];
                }
            }
        };
        // x-row prefetch (one tap ahead, registers): removes serially-exposed
        // L2 latency behind every per-tap __syncthreads.
        short8 xc0, xc1, xn0, xn1;
        auto ldX = [&](int tap, short8& o0, short8& o1) {
            int dh = tap / 9 - 1, dw = (tap / 3) % 3 - 1, dd = tap % 3 - 1;
            int shift = dh * 256 + dw * 16 + dd;
            bool ok = ((unsigned)(hx + dh) < 16u) &&
                      ((unsigned)(wy + dw) < 16u) &&
                      ((unsigned)(dz + dd) < 16u);
            int row = ok ? (pos + shift + 1) : 0;
            const ushortT* xrow = xb + (size_t)row * 64 + q * 8;
            o0 = *(const short8*)xrow;
            o1 = *(const short8*)(xrow + 32);
        };

        ldW(0);
        ldX(0, xc0, xc1);
        wrW(sW);
        __syncthreads();

        #pragma unroll
        for (int tap = 0; tap < 27; tap++) {
            ushortT* cW = sW + (tap & 1) * 5120;
            bool more = (tap + 1 < 27);

            if (more) { ldW(tap + 1); ldX(tap + 1, xn0, xn1); }

            #pragma unroll
            for (int o = 0; o < 5; o++) {
                int wr2 = o * 16 + lane15;
                short8 a0 = *(const short8*)(cW + wr2 * 64 + ((q ^ (lane15 & 7)) * 8));
                short8 a1 = *(const short8*)(cW + wr2 * 64 + (((4 + q) ^ (lane15 & 7)) * 8));
                accA[o] = __builtin_amdgcn_mfma_f32_16x16x32_bf16(a0, xc0, accA[o], 0, 0, 0);
                accB[o] = __builtin_amdgcn_mfma_f32_16x16x32_bf16(a1, xc1, accB[o], 0, 0, 0);
            }

            if (more) wrW(sW + ((tap + 1) & 1) * 5120);
            __syncthreads();
            xc0 = xn0; xc1 = xn1;
        }

        #pragma unroll
        for (int o = 0; o < 5; o++) {
            float4v accT = accA[o] + accB[o];
            if (o == 0) {
                #pragma unroll
                for (int r = 0; r < 4; r++) {
                    int ol = q * 4 + r;
                    float v = accT[r];
                    if (ol < 8)
                        Mt[((size_t)(b * NN + pos)) * 8 + ol] = f2bf(v + qb[ol] * LOG2E);
                    else
                        Nt[((size_t)(b * NN + pos)) * 8 + (ol - 8)] = f2bf(v + kb[ol - 8]);
                }
            } else {
                #pragma unroll
                for (int r = 0; r < 4; r++) {
                    int oc = (o - 1) * 16 + q * 4 + r;
                    Wvt[((size_t)(b * 64 + oc)) * NN + pos] = f2bf(accT[r] + vb[oc]);
                }
            }
        }
    }
}

// ---------------- GSA flash (blocks 0..511) + TSA-reduce tail (blocks 512..767) ----------------
__global__ __launch_bounds__(256, 3) void k_gsa(const ushortT* __restrict__ Mtb,
                                                const ushortT* __restrict__ Ntb,
                                                const ushortT* __restrict__ Wvtb,
                                                float* __restrict__ pMg, float* __restrict__ pLg,
                                                ushortT* __restrict__ pAccG,
                                                const float* __restrict__ pMt,
                                                const float* __restrict__ pLt,
                                                const ushortT* __restrict__ pAccT,
                                                const float* __restrict__ xpe,
                                                const float* __restrict__ lam1,
                                                float* __restrict__ out) {
    __shared__ ushortT sm[20480];
    int bx = blockIdx.x, t = threadIdx.x;
    if (bx < 512) {
        int it = bx & 31, jc = (bx >> 5) & 7, b = bx >> 8;
        flash_body<0>(it, jc, b, t, Mtb, Ntb, Wvtb, pMg, pLg, pAccG,
                      sm, sm + 8192, sm + 16384);
    } else {
        // TSA reduce + epilogue: out = lam1*tsa + xpe  (runs concurrent with GSA flash)
        int rb = bx - 512;                 // 0..255
        int b = rb >> 7, n0 = (rb & 127) * 32;
        float (*sT_)[65] = (float(*)[65])sm;
        int pp = t >> 3, seg = t & 7, n = n0 + pp;

        float vt[8];
        reduce_set(pMt, pLt, pAccT, b, n, seg, vt);
        #pragma unroll
        for (int e = 0; e < 8; e++) sT_[pp][seg * 8 + e] = vt[e];
        __syncthreads();

        int c = t >> 2, ns = (t & 3) * 8;
        float la1 = lam1[0];
        size_t ob = ((size_t)(b * 64 + c)) * NN + n0 + ns;
        const float* xp = xpe + ob;
        #pragma unroll
        for (int j = 0; j < 8; j += 4) {
            float4 ov;
            ov.x = la1 * sT_[ns + j + 0][c] + xp[j + 0];
            ov.y = la1 * sT_[ns + j + 1][c] + xp[j + 1];
            ov.z = la1 * sT_[ns + j + 2][c] + xp[j + 2];
            ov.w = la1 * sT_[ns + j + 3][c] + xp[j + 3];
            *(float4*)(out + ob + j) = ov;
        }
    }
}

// ---------------- Final: out += lam2 * gsa ----------------
__global__ __launch_bounds__(256) void k_reduce_g(const float* __restrict__ pMg,
                                                  const float* __restrict__ pLg,
                                                  const ushortT* __restrict__ pAccG,
                                                  const float* __restrict__ lam2,
                                                  float* __restrict__ out) {
    __shared__ float sG[32][65];
    int t = threadIdx.x;
    int b = blockIdx.y;
    int n0 = blockIdx.x * 32;
    int pp = t >> 3, seg = t & 7;
    int n = n0 + pp;

    float vg[8];
    reduce_set(pMg, pLg, pAccG, b, n, seg, vg);
    #pragma unroll
    for (int e = 0; e < 8; e++) sG[pp][seg * 8 + e] = vg[e];
    __syncthreads();

    int c = t >> 2, ns = (t & 3) * 8;
    float la2 = lam2[0];
    size_t ob = ((size_t)(b * 64 + c)) * NN + n0 + ns;
    #pragma unroll
    for (int j = 0; j < 8; j += 4) {
        float4 cur = *(const float4*)(out + ob + j);
        cur.x += la2 * sG[ns + j + 0][c];
        cur.y += la2 * sG[ns + j + 1][c];
        cur.z += la2 * sG[ns + j + 2][c];
        cur.w += la2 * sG[ns + j + 3][c];
        *(float4*)(out + ob + j) = cur;
    }
}

extern "C" void kernel_launch(void* const* d_in, const int* in_sizes, int n_in,
                              void* d_out, int out_size, void* d_ws, size_t ws_size,
                              hipStream_t stream) {
    const float* x    = (const float*)d_in[0];
    const float* Wq   = (const float*)d_in[1];
    const float* Wk   = (const float*)d_in[2];
    const float* Wv   = (const float*)d_in[3];
    const float* qw   = (const float*)d_in[4];
    const float* qb   = (const float*)d_in[5];
    const float* kw   = (const float*)d_in[6];
    const float* kb   = (const float*)d_in[7];
    const float* vw   = (const float*)d_in[8];
    const float* vb   = (const float*)d_in[9];
    const float* lam1 = (const float*)d_in[10];
    const float* lam2 = (const float*)d_in[11];
    float* out = (float*)d_out;

    char* W = (char*)d_ws;
    float*   xpe   = (float*)(W);                               // 2 MB
    ushortT* Qb    = (ushortT*)(W + (2u << 20));                // 1 MB
    ushortT* Kb    = (ushortT*)(W + (3u << 20));                // 1 MB
    ushortT* Vtb   = (ushortT*)(W + (4u << 20));                // 1 MB
    ushortT* Mtb   = (ushortT*)(W + (5u << 20));                // 128 KB
    ushortT* Ntb   = (ushortT*)(W + (5u << 20) + (1u << 17));   // 128 KB
    ushortT* Wvtb  = (ushortT*)(W + (5u << 20) + (2u << 17));   // 1 MB
    ushortT* Xt    = (ushortT*)(W + (6u << 20) + (2u << 17));   // ~1.0 MB
    ushortT* Wr    = (ushortT*)(W + (7u << 20) + (1u << 19));   // ~0.3 MB
    float*   pLt   = (float*)(W + (8u << 20));                  // 256 KB (NJ=8)
    float*   pLg   = (float*)(W + (8u << 20) + (1u << 18));     // 256 KB
    float*   pMt   = (float*)(W + (8u << 20) + (2u << 18));     // 256 KB
    float*   pMg   = (float*)(W + (8u << 20) + (3u << 18));     // 256 KB
    ushortT* pAccT = (ushortT*)(W + (9u << 20));                // 8 MB
    ushortT* pAccG = (ushortT*)(W + (17u << 20));               // 8 MB (ends 25 MB)

    // 1. x_pe + Xt + QKV (blocks 0..127) + conv weight reorg (blocks 128..667)
    k_pre<<<dim3(128 + WQKV_OFF / 256), dim3(256), 0, stream>>>(
        x, qw, kw, vw, Wq, Wk, Wv, xpe, Xt, Wr, Qb, Kb, Vtb);
    // 2. fused conv (128 blocks) + TSA flash (512 blocks)
    k_tsacv<<<dim3(128 + 32 * NJ * BB), dim3(256), 0, stream>>>(
        Qb, Kb, Vtb, Xt, Wr, qb, kb, vb, Mtb, Ntb, Wvtb, pMt, pLt, pAccT);
    // 3. GSA flash (512 blocks) + concurrent TSA-reduce/epilogue (256 blocks)
    k_gsa<<<dim3(512 + 256), dim3(256), 0, stream>>>(
        Mtb, Ntb, Wvtb, pMg, pLg, pAccG, pMt, pLt, pAccT, xpe, lam1, out);
    // 4. final GSA reduce: out += lam2 * gsa
    k_reduce_g<<<dim3(NN / 32, BB), dim3(256), 0, stream>>>(
        pMg, pLg, pAccG, lam2, out);
}